// Round 1
// 231.034 us; speedup vs baseline: 1.2061x; 1.2061x over previous
//
#include <hip/hip_runtime.h>
#include <hip/hip_bf16.h>

#define BB 512
#define VV 6890
#define NJ 24
#define NBETA 10
#define NP 207          // (24-1)*9
#define N3 (VV*3)       // 20670
#define TBAT 16         // batch tile in k_posed (was 32: grid too small, occupancy-bound)

// d_out element offsets (fp32), concatenated in return order:
// verts (B,V,3), posed_joints (B,J,3), A (B,J,4,4), transforms (B,J,4,4), v_posed (B,V,3)
#define OFF_VERTS 0
#define OFF_PJ   (BB*VV*3)
#define OFF_A    (OFF_PJ + BB*NJ*3)
#define OFF_TF   (OFF_A + BB*NJ*16)
#define OFF_VP   (OFF_TF + BB*NJ*16)

// ws layout (fp32 elements) — total ~1.2 MB
#define WS_JTJS 0                    // 24*33: per joint [JT[3] | JS[3][10]]
#define WS_PF   (WS_JTJS + NJ*33)    // B*207 pose_feature
#define WS_A    (WS_PF + BB*NP)      // B*24*16 fp32 A

// SMPL parents are a compile-time constant in the reference — hardcoded.
__constant__ int c_par[NJ] = {-1, 0, 0, 0, 1, 2, 3, 4, 5, 6, 7, 8,
                              9, 9, 9, 12, 13, 14, 16, 17, 18, 19, 20, 21};

// ------------------------------------------------- K1: JT = Jreg@vt, JS = Jreg@sd
// grid = 24*33 blocks; block reduces one (j, idx) dot over V. Batch-independent.
__global__ void k_jreg(const float* __restrict__ jr,
                       const float* __restrict__ vt,
                       const float* __restrict__ sd,
                       float* __restrict__ ws) {
    int j = blockIdx.x / 33, idx = blockIdx.x % 33;
    int t = threadIdx.x;
    float acc = 0.f;
    for (int v = t; v < VV; v += 256) {
        float a = jr[j * VV + v];
        float x = (idx < 3) ? vt[v * 3 + idx] : sd[v * 30 + (idx - 3)];
        acc += a * x;
    }
    __shared__ float red[256];
    red[t] = acc;
    __syncthreads();
    for (int s = 128; s > 0; s >>= 1) {
        if (t < s) red[t] += red[t + s];
        __syncthreads();
    }
    if (t == 0) ws[WS_JTJS + j * 33 + idx] = red[0];
}

// ------------------------------- K2: Jloc, Rodrigues, chain, A/transforms/joints
__global__ __launch_bounds__(64) void k_chain(
        const float* __restrict__ betas,
        const float* __restrict__ pose,
        const float* __restrict__ ws_jtjs,
        float* __restrict__ ws_pf,
        float* __restrict__ ws_A,
        float* __restrict__ out) {
    int b = blockIdx.x;
    int t = threadIdx.x;
    __shared__ float Jl[NJ][3];
    __shared__ float tm[NJ][16];
    __shared__ float ch[NJ][16];
    float R[9];

    if (t < NJ) {
        int j = t;
        float bb[NBETA];
#pragma unroll
        for (int l = 0; l < NBETA; l++) bb[l] = betas[b * NBETA + l];
#pragma unroll
        for (int k = 0; k < 3; k++) {
            float acc = ws_jtjs[j * 33 + k];
#pragma unroll
            for (int l = 0; l < NBETA; l++) acc += bb[l] * ws_jtjs[j * 33 + 3 + k * NBETA + l];
            Jl[j][k] = acc;
        }
        // Rodrigues, matching reference: angle = ||aa + 1e-8||, rd = aa/angle
        float ax = pose[b * NJ * 3 + j * 3 + 0];
        float ay = pose[b * NJ * 3 + j * 3 + 1];
        float az = pose[b * NJ * 3 + j * 3 + 2];
        float e0 = ax + 1e-8f, e1 = ay + 1e-8f, e2 = az + 1e-8f;
        float ang = sqrtf(e0 * e0 + e1 * e1 + e2 * e2);
        float inv = 1.f / ang;
        float rx = ax * inv, ry = ay * inv, rz = az * inv;
        float sn = sinf(ang), cs = cosf(ang);
        float Km[9] = {0.f, -rz, ry, rz, 0.f, -rx, -ry, rx, 0.f};
#pragma unroll
        for (int r = 0; r < 3; r++)
#pragma unroll
            for (int c = 0; c < 3; c++) {
                float kk = Km[3 * r + 0] * Km[0 + c] + Km[3 * r + 1] * Km[3 + c] +
                           Km[3 * r + 2] * Km[6 + c];
                R[3 * r + c] = ((r == c) ? 1.f : 0.f) + sn * Km[3 * r + c] + (1.f - cs) * kk;
            }
        if (j >= 1) {
#pragma unroll
            for (int e = 0; e < 9; e++) {
                int r = e / 3, c = e % 3;
                ws_pf[b * NP + (j - 1) * 9 + e] = R[e] - ((r == c) ? 1.f : 0.f);
            }
        }
    }
    __syncthreads();
    if (t < NJ) {
        int j = t;
        int p = c_par[j];
        int ps = (p < 0) ? 0 : p;
#pragma unroll
        for (int r = 0; r < 3; r++) {
            tm[j][r * 4 + 0] = R[3 * r + 0];
            tm[j][r * 4 + 1] = R[3 * r + 1];
            tm[j][r * 4 + 2] = R[3 * r + 2];
            tm[j][r * 4 + 3] = (j == 0) ? Jl[j][r] : (Jl[j][r] - Jl[ps][r]);
        }
        tm[j][12] = 0.f; tm[j][13] = 0.f; tm[j][14] = 0.f; tm[j][15] = 1.f;
    }
    __syncthreads();
    if (t < 16) ch[0][t] = tm[0][t];
    __syncthreads();
    for (int i = 1; i < NJ; i++) {
        if (t < 16) {
            int r = t >> 2, c = t & 3;
            int p = c_par[i];
            ch[i][t] = ch[p][4 * r + 0] * tm[i][0 + c] + ch[p][4 * r + 1] * tm[i][4 + c] +
                       ch[p][4 * r + 2] * tm[i][8 + c] + ch[p][4 * r + 3] * tm[i][12 + c];
        }
        __syncthreads();
    }
    if (t < NJ) {
        int j = t;
        float ib[4];
#pragma unroll
        for (int p = 0; p < 4; p++)
            ib[p] = ch[j][4 * p + 0] * Jl[j][0] + ch[j][4 * p + 1] * Jl[j][1] +
                    ch[j][4 * p + 2] * Jl[j][2];
#pragma unroll
        for (int e = 0; e < 16; e++) {
            int r = e >> 2, c = e & 3;
            float tr = ch[j][e];
            float Ae = tr - ((c == 3) ? ib[r] : 0.f);
            out[OFF_TF + (size_t)(b * NJ + j) * 16 + e] = tr;
            out[OFF_A + (size_t)(b * NJ + j) * 16 + e] = Ae;
            ws_A[(size_t)(b * NJ + j) * 16 + e] = Ae;
        }
#pragma unroll
        for (int k = 0; k < 3; k++)
            out[OFF_PJ + (size_t)(b * NJ + j) * 3 + k] = ch[j][4 * k + 3];
    }
}

// ----------- K3 (fused, batch-tiled): v_posed = v_template + sd@betas + pf@posedirs
// grid = (ceil(N3/512), BB/TBAT); each thread does 2 consecutive n, TBAT batches.
// pf/betas are WORKGROUP-UNIFORM -> read via uniform global indices so the
// compiler emits s_load (SGPR operand of v_fma), freeing the LDS pipe entirely.
// No LDS, no barriers -> occupancy limited only by VGPRs (~90) and grid (1312 wg).
__global__ __launch_bounds__(256, 4) void k_posed(
        const float* __restrict__ vt,
        const float* __restrict__ sd,
        const float* __restrict__ betas,
        const float* __restrict__ pd,
        const float* __restrict__ ws_pf,
        float* __restrict__ out) {
    int b0 = blockIdx.y * TBAT;
    int n0 = (blockIdx.x * 256 + threadIdx.x) * 2;
    if (n0 >= N3) return;

    float acc0[TBAT], acc1[TBAT];
#pragma unroll
    for (int bi = 0; bi < TBAT; bi++) { acc0[bi] = 0.f; acc1[bi] = 0.f; }

    // 207 = 23 chunks of 9
    for (int p0 = 0; p0 < NP; p0 += 9) {
        float pdv0[9], pdv1[9];
#pragma unroll
        for (int pc = 0; pc < 9; pc++) {
            const float2 v = *(const float2*)&pd[(size_t)(p0 + pc) * N3 + n0];
            pdv0[pc] = v.x; pdv1[pc] = v.y;
        }
#pragma unroll
        for (int bi = 0; bi < TBAT; bi++) {
            const float* __restrict__ pfr = &ws_pf[(size_t)(b0 + bi) * NP + p0];  // uniform
#pragma unroll
            for (int pc = 0; pc < 9; pc++) {
                float w = pfr[pc];          // s_load: SGPR operand
                acc0[bi] += w * pdv0[pc];
                acc1[bi] += w * pdv1[pc];
            }
        }
    }

    float base0 = vt[n0], base1 = vt[n0 + 1];
    float sdv0[NBETA], sdv1[NBETA];
#pragma unroll
    for (int l = 0; l < NBETA; l++) {
        sdv0[l] = sd[(size_t)n0 * NBETA + l];
        sdv1[l] = sd[(size_t)(n0 + 1) * NBETA + l];
    }
#pragma unroll
    for (int bi = 0; bi < TBAT; bi++) {
        const float* __restrict__ br = &betas[(size_t)(b0 + bi) * NBETA];  // uniform
        float s0 = base0 + acc0[bi], s1 = base1 + acc1[bi];
#pragma unroll
        for (int l = 0; l < NBETA; l++) {
            float bl = br[l];               // s_load
            s0 += bl * sdv0[l];
            s1 += bl * sdv1[l];
        }
        float2 o; o.x = s0; o.y = s1;
        *(float2*)&out[OFF_VP + (size_t)(b0 + bi) * N3 + n0] = o;
    }
}

// --------------------------------------------- K4: T = lw@A ; verts = T.vposed
// A rows are workgroup-uniform -> scalar loads (no LDS). lw vectorized float4
// (v*96 bytes is always 16B-aligned).
__global__ void k_verts(const float* __restrict__ lw,
                        const float* __restrict__ ws_A,
                        float* __restrict__ out) {
    int b = blockIdx.y;
    int v = blockIdx.x * 256 + threadIdx.x;
    if (v >= VV) return;

    float wv[NJ];
#pragma unroll
    for (int j0 = 0; j0 < NJ; j0 += 4) {
        const float4 w4 = *(const float4*)&lw[(size_t)v * NJ + j0];
        wv[j0 + 0] = w4.x; wv[j0 + 1] = w4.y; wv[j0 + 2] = w4.z; wv[j0 + 3] = w4.w;
    }

    float T[12];
#pragma unroll
    for (int e = 0; e < 12; e++) T[e] = 0.f;
    const float* __restrict__ Ab = ws_A + (size_t)b * NJ * 16;
#pragma unroll
    for (int j = 0; j < NJ; j++) {
        const float* __restrict__ Aj = Ab + j * 16;   // uniform -> s_load rows
        float wj = wv[j];
#pragma unroll
        for (int e = 0; e < 12; e++) T[e] += wj * Aj[e];
    }

    size_t base = (size_t)(b * VV + v) * 3;
    float x = out[OFF_VP + base + 0];
    float y = out[OFF_VP + base + 1];
    float z = out[OFF_VP + base + 2];
#pragma unroll
    for (int p = 0; p < 3; p++) {
        out[OFF_VERTS + base + p] =
            T[4 * p + 0] * x + T[4 * p + 1] * y + T[4 * p + 2] * z + T[4 * p + 3];
    }
}

extern "C" void kernel_launch(void* const* d_in, const int* in_sizes, int n_in,
                              void* d_out, int out_size, void* d_ws, size_t ws_size,
                              hipStream_t stream) {
    const float* betas = (const float*)d_in[0];
    const float* pose  = (const float*)d_in[1];
    const float* vt    = (const float*)d_in[2];
    const float* sd    = (const float*)d_in[3];
    const float* pd    = (const float*)d_in[4];
    const float* jr    = (const float*)d_in[5];
    const float* lw    = (const float*)d_in[6];
    float* out = (float*)d_out;
    float* ws = (float*)d_ws;

    k_jreg<<<NJ * 33, 256, 0, stream>>>(jr, vt, sd, ws);
    k_chain<<<BB, 64, 0, stream>>>(betas, pose, ws + WS_JTJS, ws + WS_PF,
                                   ws + WS_A, out);
    k_posed<<<dim3((N3 / 2 + 255) / 256, BB / TBAT), 256, 0, stream>>>(
        vt, sd, betas, pd, ws + WS_PF, out);
    k_verts<<<dim3((VV + 255) / 256, BB), 256, 0, stream>>>(lw, ws + WS_A, out);
}